// Round 19
// baseline (429.929 us; speedup 1.0000x reference)
//
#include <hip/hip_runtime.h>
#include <hip/hip_bf16.h>
#include <cstdint>
#include <cstddef>

// CFnetFilter: w_ij = segment_sum(ssp(ssp(dijk@W1+b1)@W2+b2), seg_j)
//
// R19 = R18 (405us champion) + three algebraic instruction folds:
//  (d) bias folded into MFMA accumulator INIT (feature is j-constant across
//      mt in the swapped layout) -> -64 v_add/thread.
//  (e) final w = u2*ln2 - ln2 folded into the reduce flush: store u2; a
//      segment's Sum(w) = ln2*(Sum(u2) - cnt), cnt tracked in the scalar
//      seg loop -> -32 v_fma/thread (phase 4 == phase 2 now).
//  (f) staging cvts via v_cvt_pk_bf16_f32 (2-at-a-time) -> -16 insts/thread.
// All else R18-verbatim (swapped MFMA, b64 epilogue stores, base-2 softplus,
// hoisted swizzle addrs, paired-column reduce).

typedef float  f32x4  __attribute__((ext_vector_type(4)));
typedef __bf16 bf16x8 __attribute__((ext_vector_type(8)));
typedef uint32_t u32x2 __attribute__((ext_vector_type(2)));
typedef uint32_t u32x4 __attribute__((ext_vector_type(4)));

// may_alias views for LDS type-punning (R5 lesson)
typedef uint32_t u32a    __attribute__((may_alias));
typedef u32x2    u32x2a  __attribute__((may_alias));
typedef u32x4    u32x4a  __attribute__((may_alias));
typedef bf16x8   bf16x8a __attribute__((may_alias));

static constexpr int   N_TRIPLES = 2000000;
static constexpr int   DIM       = 128;
static constexpr int   NSEG      = 100000;
static constexpr int   ROWS      = 128;     // rows per block (2e6 / 128 exact)
static constexpr float LOG2F_    = 0.6931471805599453f;   // ln2
static constexpr float LOG2E_    = 1.4426950408889634f;   // 1/ln2

// base-2 softplus core: u = max(y,0) + log2(1 + 2^-|y|)
__device__ __forceinline__ float sp2_(float y) {
  float t = __builtin_amdgcn_exp2f(-__builtin_fabsf(y));   // v_exp with -abs mods
  return fmaxf(y, 0.0f) + __builtin_amdgcn_logf(1.0f + t); // v_log = log2
}

// packed f32x2 -> bf16x2 (RNE); low16 = a, high16 = b
__device__ __forceinline__ uint32_t cvtpk_(float a, float b) {
  uint32_t r;
  asm("v_cvt_pk_bf16_f32 %0, %1, %2" : "=v"(r) : "v"(a), "v"(b));
  return r;
}

// WT1 = (W1*log2e)^T bf16 ; WT2 = W2^T bf16  (frags contiguous in k)
__global__ void wt_kernel(const float* __restrict__ W1, const float* __restrict__ W2,
                          __bf16* __restrict__ WT) {
  int t = blockIdx.x * 256 + threadIdx.x;   // 0..16383
  int k = t >> 7;
  int n = t & 127;
  WT[n * 128 + k]         = (__bf16)(W1[t] * LOG2E_);
  WT[16384 + n * 128 + k] = (__bf16)W2[t];
}

// b1p[n] = b1[n]*log2e ;  b2p[n] = (b2[n] - ln2*sum_k W2[k][n]) * log2e
__global__ void bias_kernel(const float* __restrict__ b1, const float* __restrict__ W2,
                            const float* __restrict__ b2,
                            float* __restrict__ b1p, float* __restrict__ b2p) {
  int n = threadIdx.x;
  float s = 0.0f;
  #pragma unroll 8
  for (int k = 0; k < 128; ++k) s += W2[k * 128 + n];
  b1p[n] = b1[n] * LOG2E_;
  b2p[n] = (b2[n] - LOG2F_ * s) * LOG2E_;
}

__global__ __launch_bounds__(512, 6) void fused_kernel(
    const float* __restrict__ dijk, const int* __restrict__ seg,
    const __bf16* __restrict__ WT,
    const float* __restrict__ b1v, const float* __restrict__ b2p,
    float* __restrict__ out)
{
  __shared__ __bf16 tile[ROWS * DIM];   // 32 KB: A, then u1, then u2

  const int tid  = threadIdx.x;         // 0..511
  const int lane = tid & 63;
  const int wave = tid >> 6;            // 0..7 -> feature slice [16w, 16w+16)
  const int l15  = lane & 15;
  const int g    = lane >> 4;           // k-group
  const int r0   = blockIdx.x * ROWS;

  char* tb = (char*)tile;

  // ---- phase 0: stage A = bf16(dijk rows) -> LDS (swizzled), cvt_pk ----
  {
    int row = tid >> 2, q = tid & 3;
    const float* src = dijk + (size_t)(r0 + row) * DIM + q * 32;
    char* dst = tb + row * 256;
    int swz = (row & 7) << 4;
    #pragma unroll
    for (int u = 0; u < 4; ++u) {
      f32x4 v0 = *(const f32x4*)(src + u * 8);
      f32x4 v1 = *(const f32x4*)(src + u * 8 + 4);
      u32x4 p;
      p[0] = cvtpk_(v0[0], v0[1]);
      p[1] = cvtpk_(v0[2], v0[3]);
      p[2] = cvtpk_(v1[0], v1[1]);
      p[3] = cvtpk_(v1[2], v1[3]);
      *(u32x4a*)(dst + ((q * 64 + u * 16) ^ swz)) = p;
    }
  }

  const int colw = wave * 16 + l15;       // WT row this lane supplies (A-frag)
  const int nb   = wave * 16 + g * 4;     // first feature col of this lane's C/D
  const f32x4 binit1 = { b1v[nb], b1v[nb + 1], b1v[nb + 2], b1v[nb + 3] };
  const f32x4 binit2 = { b2p[nb], b2p[nb + 1], b2p[nb + 2], b2p[nb + 3] };

  // hoisted addressing (row&7 is mt-invariant since 16 % 8 == 0):
  const int  swA = (l15 & 7) << 4;
  const char* abase = tb + l15 * 256;     // + mt*4096
  uint32_t bo[4];
  #pragma unroll
  for (int ks = 0; ks < 4; ++ks) bo[ks] = (uint32_t)((ks * 64 + g * 16) ^ swA);
  // epilogue b64 stores: row = mt*16 + l15, feature bytes nb*2 (8B aligned)
  const uint32_t wsb = (uint32_t)(l15 * 256 + ((nb * 2) ^ swA));   // + mt*4096

  __syncthreads();   // [1] A-tile complete

  // ---- phase 1: GEMM1, swapped: D = WT1slice . A^T + bias1(init) ----
  f32x4 acc[8];
  {
    bf16x8 bf1[4];
    #pragma unroll
    for (int ks = 0; ks < 4; ++ks)
      bf1[ks] = *(const bf16x8*)(WT + colw * 128 + ks * 32 + g * 8);

    #pragma unroll
    for (int mt = 0; mt < 8; ++mt) acc[mt] = binit1;
    #pragma unroll
    for (int mt = 0; mt < 8; ++mt) {
      const char* pm = abase + mt * 4096;
      #pragma unroll
      for (int ks = 0; ks < 4; ++ks) {
        bf16x8 a = *(const bf16x8a*)(pm + bo[ks]);
        acc[mt] = __builtin_amdgcn_mfma_f32_16x16x32_bf16(bf1[ks], a, acc[mt], 0, 0, 0);
      }
    }
  }

  __syncthreads();   // [2] all A-reads done -> tile reusable for u1

  // ---- phase 2: u1 = sp2(y1) -> tile; b64 stores ----
  #pragma unroll
  for (int mt = 0; mt < 8; ++mt) {
    u32x2 p;
    p[0] = cvtpk_(sp2_(acc[mt][0]), sp2_(acc[mt][1]));
    p[1] = cvtpk_(sp2_(acc[mt][2]), sp2_(acc[mt][3]));
    *(u32x2a*)(tb + wsb + mt * 4096) = p;
  }

  __syncthreads();   // [3] u1 complete

  // ---- phase 3: GEMM2, swapped (W2 unscaled; ln2*log2e = 1) ----
  f32x4 acc2[8];
  {
    bf16x8 bf2[4];
    #pragma unroll
    for (int ks = 0; ks < 4; ++ks)
      bf2[ks] = *(const bf16x8*)(WT + 16384 + colw * 128 + ks * 32 + g * 8);

    #pragma unroll
    for (int mt = 0; mt < 8; ++mt) acc2[mt] = binit2;
    #pragma unroll
    for (int mt = 0; mt < 8; ++mt) {
      const char* pm = abase + mt * 4096;
      #pragma unroll
      for (int ks = 0; ks < 4; ++ks) {
        bf16x8 a = *(const bf16x8a*)(pm + bo[ks]);
        acc2[mt] = __builtin_amdgcn_mfma_f32_16x16x32_bf16(bf2[ks], a, acc2[mt], 0, 0, 0);
      }
    }
  }

  __syncthreads();   // [4] all u1-reads done -> tile reusable for u2

  // ---- phase 4: u2 = sp2(y2) -> tile (w folded into reduce flush) ----
  #pragma unroll
  for (int mt = 0; mt < 8; ++mt) {
    u32x2 p;
    p[0] = cvtpk_(sp2_(acc2[mt][0]), sp2_(acc2[mt][1]));
    p[1] = cvtpk_(sp2_(acc2[mt][2]), sp2_(acc2[mt][3]));
    *(u32x2a*)(tb + wsb + mt * 4096) = p;
  }

  __syncthreads();   // [5] u2 complete, visible to all

  // ---- phase 5: segmented reduce; w-sum = ln2*(sum(u2) - cnt) per flush ----
  {
    const int colb = (tid & 63) * 2;
    const int hh   = tid >> 6;           // 0..7
    const int rbeg = hh * 16;
    const int* sp = seg + r0;
    const char* rp[8];
    #pragma unroll
    for (int k = 0; k < 8; ++k)
      rp[k] = tb + rbeg * 256 + ((colb * 2) ^ (k << 4));
    float a0 = 0.0f, a1 = 0.0f;
    int cnt = 0;
    int cur = sp[rbeg];
    #pragma unroll
    for (int i = 0; i < 16; ++i) {
      int s = sp[rbeg + i];
      if (s != cur) {
        float c = -LOG2F_ * (float)cnt;
        atomicAdd(out + (size_t)cur * DIM + colb,     __builtin_fmaf(a0, LOG2F_, c));
        atomicAdd(out + (size_t)cur * DIM + colb + 1, __builtin_fmaf(a1, LOG2F_, c));
        a0 = 0.0f; a1 = 0.0f; cnt = 0; cur = s;
      }
      uint32_t w = *(const u32a*)(rp[i & 7] + i * 256);
      a0 += __uint_as_float(w << 16);          // bf16 lo -> f32
      a1 += __uint_as_float(w & 0xffff0000u);  // bf16 hi -> f32
      ++cnt;
    }
    float c = -LOG2F_ * (float)cnt;
    atomicAdd(out + (size_t)cur * DIM + colb,     __builtin_fmaf(a0, LOG2F_, c));
    atomicAdd(out + (size_t)cur * DIM + colb + 1, __builtin_fmaf(a1, LOG2F_, c));
  }
}

extern "C" void kernel_launch(void* const* d_in, const int* in_sizes, int n_in,
                              void* d_out, int out_size, void* d_ws, size_t ws_size,
                              hipStream_t stream) {
  const float* dijk = (const float*)d_in[0];
  const int*   seg  = (const int*)d_in[1];
  const float* W1   = (const float*)d_in[2];
  const float* b1   = (const float*)d_in[3];
  const float* W2   = (const float*)d_in[4];
  const float* b2   = (const float*)d_in[5];
  float* out = (float*)d_out;

  float*  b1p = (float*)d_ws;                       // 128 f32
  float*  b2p = (float*)((char*)d_ws + 512);        // 128 f32
  __bf16* WT  = (__bf16*)((char*)d_ws + 1024);      // 2 * 128*128 bf16 = 64 KB

  // empty segments must be exactly 0; memset re-zeroes every replay
  (void)hipMemsetAsync(out, 0, (size_t)NSEG * DIM * sizeof(float), stream);

  wt_kernel<<<64, 256, 0, stream>>>(W1, W2, WT);
  bias_kernel<<<1, 128, 0, stream>>>(b1, W2, b2, b1p, b2p);

  fused_kernel<<<N_TRIPLES / ROWS, 512, 0, stream>>>(dijk, seg, WT, b1p, b2p, out);
}

// Round 20
// 405.657 us; speedup vs baseline: 1.0598x; 1.0598x over previous
//
#include <hip/hip_runtime.h>
#include <hip/hip_bf16.h>
#include <cstdint>
#include <cstddef>

// CFnetFilter: w_ij = segment_sum(ssp(ssp(dijk@W1+b1)@W2+b2), seg_j)
//
// R20 = R18 VERBATIM (405us champion; R19's three extra folds regressed to
// 430 -- bias-init added AGPR copy chains, flush-fold put work on the serial
// reduce path). Reverting per pre-commitment; if ~405 reproduces, this
// structure is the practical floor (composite issue-bound ~330-390us;
// occupancy/DS/overlap/atomic levers all independently nulled R13-R17).
//
// Structure: 512-thr blocks (8 waves x 16 cols), 128-row tile, single 32KB
// LDS buffer phase-multiplexed (A -> u1 -> wijk); swapped-operand MFMA
// (D = WTslice . tile^T) so epilogue is 2x v_cvt_pk_bf16_f32 + 1 ds_write_b64
// per 4 outputs; base-2 softplus with scales folded into W1/b1/b2
// (W2 invariant since ln2*log2e = 1); 3-bit XOR swizzle; hoisted addressing;
// paired-column scalar-steered segmented reduce with fire-and-forget atomics.

typedef float  f32x4  __attribute__((ext_vector_type(4)));
typedef __bf16 bf16x8 __attribute__((ext_vector_type(8)));
typedef uint32_t u32x2 __attribute__((ext_vector_type(2)));

// may_alias views for LDS type-punning (R5 lesson)
typedef uint32_t u32a    __attribute__((may_alias));
typedef u32x2    u32x2a  __attribute__((may_alias));
typedef bf16x8   bf16x8a __attribute__((may_alias));
typedef __bf16   bf16a   __attribute__((may_alias));

static constexpr int   N_TRIPLES = 2000000;
static constexpr int   DIM       = 128;
static constexpr int   NSEG      = 100000;
static constexpr int   ROWS      = 128;     // rows per block (2e6 / 128 exact)
static constexpr float LOG2F_    = 0.6931471805599453f;   // ln2
static constexpr float LOG2E_    = 1.4426950408889634f;   // 1/ln2

// base-2 softplus core: u = max(y,0) + log2(1 + 2^-|y|)
__device__ __forceinline__ float sp2_(float y) {
  float t = __builtin_amdgcn_exp2f(-__builtin_fabsf(y));   // v_exp with -abs mods
  return fmaxf(y, 0.0f) + __builtin_amdgcn_logf(1.0f + t); // v_log = log2
}

// packed f32x2 -> bf16x2 (RNE); low16 = a, high16 = b
__device__ __forceinline__ uint32_t cvtpk_(float a, float b) {
  uint32_t r;
  asm("v_cvt_pk_bf16_f32 %0, %1, %2" : "=v"(r) : "v"(a), "v"(b));
  return r;
}

// WT1 = (W1*log2e)^T bf16 ; WT2 = W2^T bf16  (frags contiguous in k)
__global__ void wt_kernel(const float* __restrict__ W1, const float* __restrict__ W2,
                          __bf16* __restrict__ WT) {
  int t = blockIdx.x * 256 + threadIdx.x;   // 0..16383
  int k = t >> 7;
  int n = t & 127;
  WT[n * 128 + k]         = (__bf16)(W1[t] * LOG2E_);
  WT[16384 + n * 128 + k] = (__bf16)W2[t];
}

// b1p[n] = b1[n]*log2e ;  b2p[n] = (b2[n] - ln2*sum_k W2[k][n]) * log2e
__global__ void bias_kernel(const float* __restrict__ b1, const float* __restrict__ W2,
                            const float* __restrict__ b2,
                            float* __restrict__ b1p, float* __restrict__ b2p) {
  int n = threadIdx.x;
  float s = 0.0f;
  #pragma unroll 8
  for (int k = 0; k < 128; ++k) s += W2[k * 128 + n];
  b1p[n] = b1[n] * LOG2E_;
  b2p[n] = (b2[n] - LOG2F_ * s) * LOG2E_;
}

__global__ __launch_bounds__(512, 6) void fused_kernel(
    const float* __restrict__ dijk, const int* __restrict__ seg,
    const __bf16* __restrict__ WT,
    const float* __restrict__ b1v, const float* __restrict__ b2p,
    float* __restrict__ out)
{
  __shared__ __bf16 tile[ROWS * DIM];   // 32 KB: A, then u1, then wijk

  const int tid  = threadIdx.x;         // 0..511
  const int lane = tid & 63;
  const int wave = tid >> 6;            // 0..7 -> feature slice [16w, 16w+16)
  const int l15  = lane & 15;
  const int g    = lane >> 4;           // k-group
  const int r0   = blockIdx.x * ROWS;

  char* tb = (char*)tile;

  // ---- phase 0: stage A = bf16(dijk rows) -> LDS (swizzled), cooperative ----
  {
    int row = tid >> 2, q = tid & 3;
    const float* src = dijk + (size_t)(r0 + row) * DIM + q * 32;
    char* dst = tb + row * 256;
    int swz = (row & 7) << 4;
    #pragma unroll
    for (int u = 0; u < 4; ++u) {
      f32x4 v0 = *(const f32x4*)(src + u * 8);
      f32x4 v1 = *(const f32x4*)(src + u * 8 + 4);
      bf16x8 t8;
      t8[0] = (__bf16)v0[0]; t8[1] = (__bf16)v0[1]; t8[2] = (__bf16)v0[2]; t8[3] = (__bf16)v0[3];
      t8[4] = (__bf16)v1[0]; t8[5] = (__bf16)v1[1]; t8[6] = (__bf16)v1[2]; t8[7] = (__bf16)v1[3];
      *(bf16x8a*)(dst + ((q * 64 + u * 16) ^ swz)) = t8;
    }
  }

  const int colw = wave * 16 + l15;       // WT row this lane supplies (A-frag)
  const int nb   = wave * 16 + g * 4;     // first feature col of this lane's C/D
  float bias1[4], bias2[4];
  #pragma unroll
  for (int j = 0; j < 4; ++j) {
    bias1[j] = b1v[nb + j];
    bias2[j] = b2p[nb + j];
  }

  // hoisted addressing (row&7 is mt-invariant since 16 % 8 == 0):
  // tile reads (B-frag now): row = mt*16 + l15, bytes (ks*64 + g*16) ^ swA
  const int  swA = (l15 & 7) << 4;
  const char* abase = tb + l15 * 256;     // + mt*4096
  uint32_t bo[4];
  #pragma unroll
  for (int ks = 0; ks < 4; ++ks) bo[ks] = (uint32_t)((ks * 64 + g * 16) ^ swA);
  // epilogue b64 stores: row = mt*16 + l15, feature bytes nb*2 (8B aligned)
  const uint32_t wsb = (uint32_t)(l15 * 256 + ((nb * 2) ^ swA));   // + mt*4096

  __syncthreads();   // [1] A-tile complete

  // ---- phase 1: GEMM1, swapped operands: D = WT1slice . A^T = y1^T ----
  f32x4 acc[8];
  {
    bf16x8 bf1[4];
    #pragma unroll
    for (int ks = 0; ks < 4; ++ks)
      bf1[ks] = *(const bf16x8*)(WT + colw * 128 + ks * 32 + g * 8);

    #pragma unroll
    for (int mt = 0; mt < 8; ++mt) acc[mt] = (f32x4){0.f, 0.f, 0.f, 0.f};
    #pragma unroll
    for (int mt = 0; mt < 8; ++mt) {
      const char* pm = abase + mt * 4096;
      #pragma unroll
      for (int ks = 0; ks < 4; ++ks) {
        bf16x8 a = *(const bf16x8a*)(pm + bo[ks]);
        acc[mt] = __builtin_amdgcn_mfma_f32_16x16x32_bf16(bf1[ks], a, acc[mt], 0, 0, 0);
      }
    }
  }

  __syncthreads();   // [2] all A-reads done -> tile reusable for u1

  // ---- phase 2: u1 = sp2(y1) -> tile; 4 contiguous features per b64 store ----
  #pragma unroll
  for (int mt = 0; mt < 8; ++mt) {
    float u0 = sp2_(acc[mt][0] + bias1[0]);
    float u1 = sp2_(acc[mt][1] + bias1[1]);
    float u2 = sp2_(acc[mt][2] + bias1[2]);
    float u3 = sp2_(acc[mt][3] + bias1[3]);
    u32x2 p;
    p[0] = cvtpk_(u0, u1);
    p[1] = cvtpk_(u2, u3);
    *(u32x2a*)(tb + wsb + mt * 4096) = p;
  }

  __syncthreads();   // [3] u1 complete

  // ---- phase 3: GEMM2, swapped operands (W2 unscaled; ln2*log2e = 1) ----
  f32x4 acc2[8];
  {
    bf16x8 bf2[4];
    #pragma unroll
    for (int ks = 0; ks < 4; ++ks)
      bf2[ks] = *(const bf16x8*)(WT + 16384 + colw * 128 + ks * 32 + g * 8);

    #pragma unroll
    for (int mt = 0; mt < 8; ++mt) acc2[mt] = (f32x4){0.f, 0.f, 0.f, 0.f};
    #pragma unroll
    for (int mt = 0; mt < 8; ++mt) {
      const char* pm = abase + mt * 4096;
      #pragma unroll
      for (int ks = 0; ks < 4; ++ks) {
        bf16x8 a = *(const bf16x8a*)(pm + bo[ks]);
        acc2[mt] = __builtin_amdgcn_mfma_f32_16x16x32_bf16(bf2[ks], a, acc2[mt], 0, 0, 0);
      }
    }
  }

  __syncthreads();   // [4] all u1-reads done -> tile reusable for wijk

  // ---- phase 4: w = fma(sp2(y2), ln2, -ln2) -> tile (b64 stores) ----
  #pragma unroll
  for (int mt = 0; mt < 8; ++mt) {
    float w0 = __builtin_fmaf(sp2_(acc2[mt][0] + bias2[0]), LOG2F_, -LOG2F_);
    float w1 = __builtin_fmaf(sp2_(acc2[mt][1] + bias2[1]), LOG2F_, -LOG2F_);
    float w2 = __builtin_fmaf(sp2_(acc2[mt][2] + bias2[2]), LOG2F_, -LOG2F_);
    float w3 = __builtin_fmaf(sp2_(acc2[mt][3] + bias2[3]), LOG2F_, -LOG2F_);
    u32x2 p;
    p[0] = cvtpk_(w0, w1);
    p[1] = cvtpk_(w2, w3);
    *(u32x2a*)(tb + wsb + mt * 4096) = p;
  }

  __syncthreads();   // [5] wijk complete, visible to all

  // ---- phase 5: segmented reduce (paired-column u32 form) ----
  {
    const int colb = (tid & 63) * 2;
    const int hh   = tid >> 6;           // 0..7
    const int rbeg = hh * 16;
    const int* sp = seg + r0;
    const char* rp[8];
    #pragma unroll
    for (int k = 0; k < 8; ++k)
      rp[k] = tb + rbeg * 256 + ((colb * 2) ^ (k << 4));
    float a0 = 0.0f, a1 = 0.0f;
    int cur = sp[rbeg];
    #pragma unroll
    for (int i = 0; i < 16; ++i) {
      int s = sp[rbeg + i];
      if (s != cur) {
        atomicAdd(out + (size_t)cur * DIM + colb,     a0);
        atomicAdd(out + (size_t)cur * DIM + colb + 1, a1);
        a0 = 0.0f; a1 = 0.0f; cur = s;
      }
      uint32_t w = *(const u32a*)(rp[i & 7] + i * 256);
      a0 += __uint_as_float(w << 16);          // bf16 lo -> f32
      a1 += __uint_as_float(w & 0xffff0000u);  // bf16 hi -> f32
    }
    atomicAdd(out + (size_t)cur * DIM + colb,     a0);
    atomicAdd(out + (size_t)cur * DIM + colb + 1, a1);
  }
}

extern "C" void kernel_launch(void* const* d_in, const int* in_sizes, int n_in,
                              void* d_out, int out_size, void* d_ws, size_t ws_size,
                              hipStream_t stream) {
  const float* dijk = (const float*)d_in[0];
  const int*   seg  = (const int*)d_in[1];
  const float* W1   = (const float*)d_in[2];
  const float* b1   = (const float*)d_in[3];
  const float* W2   = (const float*)d_in[4];
  const float* b2   = (const float*)d_in[5];
  float* out = (float*)d_out;

  float*  b1p = (float*)d_ws;                       // 128 f32
  float*  b2p = (float*)((char*)d_ws + 512);        // 128 f32
  __bf16* WT  = (__bf16*)((char*)d_ws + 1024);      // 2 * 128*128 bf16 = 64 KB

  // empty segments must be exactly 0; memset re-zeroes every replay
  (void)hipMemsetAsync(out, 0, (size_t)NSEG * DIM * sizeof(float), stream);

  wt_kernel<<<64, 256, 0, stream>>>(W1, W2, WT);
  bias_kernel<<<1, 128, 0, stream>>>(b1, W2, b2, b1p, b2p);

  fused_kernel<<<N_TRIPLES / ROWS, 512, 0, stream>>>(dijk, seg, WT, b1p, b2p, out);
}